// Round 1
// baseline (370.030 us; speedup 1.0000x reference)
//
#include <hip/hip_runtime.h>

// Problem constants (from reference): N=262144 rows, NX=NQ=64, NU=16, fp32.
#define NROWS 262144
#define NXc 64
#define NQc 64
#define NUc 16

// d_ws layout (floats):
//   AT   [4096]  @ 0      : AT[j*64+k]  = A[k][j]
//   C1T  [4096]  @ 4096   : C1T[j*64+i] = C1[i][j]
//   D11T [4096]  @ 8192   : D11T[i*64+k]= D11[k][i]
//   B1T  [4096]  @ 12288  : B1T[i*64+k] = B1[k][i]
//   B2T  [1024]  @ 16384  : B2T[j*64+k] = B2[k][j]
//   D12T [1024]  @ 17408  : D12T[j*64+i]= D12[i][j]
//   bv   [64]    @ 18432
//   bx   [64]    @ 18496

__global__ void prep_kernel(const float* __restrict__ A, const float* __restrict__ B1,
                            const float* __restrict__ B2, const float* __restrict__ C1,
                            const float* __restrict__ D11, const float* __restrict__ D12,
                            const float* __restrict__ bv, const float* __restrict__ bx,
                            float* __restrict__ ws) {
    int t = threadIdx.x;
    for (int idx = t; idx < 4096; idx += 256) {
        int r = idx >> 6, c = idx & 63;
        int to = c * 64 + r;
        ws[0 * 4096 + to] = A[idx];
        ws[1 * 4096 + to] = C1[idx];
        ws[2 * 4096 + to] = D11[idx];
        ws[3 * 4096 + to] = B1[idx];
    }
    for (int idx = t; idx < 1024; idx += 256) {
        int r = idx >> 4, c = idx & 15;   // 64x16 row-major in
        int to = c * 64 + r;
        ws[16384 + to] = B2[idx];
        ws[17408 + to] = D12[idx];
    }
    if (t < 64) {
        ws[18432 + t] = bv[t];
        ws[18496 + t] = bx[t];
    }
}

// One thread per row. Matrices read with wave-uniform indices -> s_load (SGPR
// broadcast), row state in VGPRs (all register-indexed loops fully unrolled).
__global__ __launch_bounds__(64, 2) void renl2_kernel(const float* __restrict__ x,
                                                      const float* __restrict__ u,
                                                      const float* __restrict__ ws,
                                                      float* __restrict__ out) {
    const float* __restrict__ AT   = ws;
    const float* __restrict__ C1T  = ws + 4096;
    const float* __restrict__ D11T = ws + 8192;
    const float* __restrict__ B1T  = ws + 12288;
    const float* __restrict__ B2T  = ws + 16384;
    const float* __restrict__ D12T = ws + 17408;
    const float* __restrict__ bv   = ws + 18432;
    const float* __restrict__ bx   = ws + 18496;

    // w_lds[i*64 + lane]: stride-1 across lanes -> conflict-free, no barrier
    // needed (each lane touches only its own column).
    __shared__ float w_lds[64 * 64];

    const int t = threadIdx.x;
    const long n = (long)blockIdx.x * 64 + t;
    const float* __restrict__ xr = x + n * 64;
    const float* __restrict__ ur = u + n * 16;

    float base[64];  // -> w precursor (bv + C1 x + D12 u + D11-subst)
    float acc[64];   // -> x_dot accumulator (bx + A x + B2 u + B1 w)
#pragma unroll
    for (int i = 0; i < 64; i++) { base[i] = bv[i]; acc[i] = bx[i]; }

    // x contribution: base += C1 x ; acc += A x   (stream x, columns via s_load)
#pragma unroll 1
    for (int j = 0; j < 64; j += 4) {
        float4 xv = *(const float4*)(xr + j);
#pragma unroll
        for (int jj = 0; jj < 4; jj++) {
            const float xs = ((const float*)&xv)[jj];
            const float* __restrict__ cc = C1T + (j + jj) * 64;
            const float* __restrict__ ac = AT + (j + jj) * 64;
#pragma unroll
            for (int i = 0; i < 64; i++) {
                base[i] += cc[i] * xs;
                acc[i] += ac[i] * xs;
            }
        }
    }

    // u contribution: base += D12 u ; acc += B2 u
#pragma unroll 1
    for (int j = 0; j < 16; j += 4) {
        float4 uv = *(const float4*)(ur + j);
#pragma unroll
        for (int jj = 0; jj < 4; jj++) {
            const float us = ((const float*)&uv)[jj];
            const float* __restrict__ dc = D12T + (j + jj) * 64;
            const float* __restrict__ bc = B2T + (j + jj) * 64;
#pragma unroll
            for (int i = 0; i < 64; i++) {
                base[i] += dc[i] * us;
                acc[i] += bc[i] * us;
            }
        }
    }

    // Forward substitution, right-looking: when base[i] is final,
    // w_i = relu(base[i]); scatter w_i into future rows via D11 column i.
    // Fully unrolled so base[] stays in registers (2016 FMAs).
#pragma unroll
    for (int i = 0; i < 64; i++) {
        const float wv = fmaxf(base[i], 0.0f);
        w_lds[i * 64 + t] = wv;
        const float* __restrict__ dcol = D11T + i * 64;
#pragma unroll
        for (int k = i + 1; k < 64; k++) base[k] += dcol[k] * wv;
    }

    // acc += B1 w  (w streamed back from LDS; B1 columns via s_load)
#pragma unroll 1
    for (int i = 0; i < 64; i++) {
        const float wv = w_lds[i * 64 + t];
        const float* __restrict__ b1c = B1T + i * 64;
#pragma unroll
        for (int k = 0; k < 64; k++) acc[k] += b1c[k] * wv;
    }

    // Store x_dot row.
    float4* __restrict__ op = (float4*)(out + n * 64);
#pragma unroll
    for (int k = 0; k < 64; k += 4) {
        float4 v;
        v.x = acc[k]; v.y = acc[k + 1]; v.z = acc[k + 2]; v.w = acc[k + 3];
        op[k >> 2] = v;
    }
}

extern "C" void kernel_launch(void* const* d_in, const int* in_sizes, int n_in,
                              void* d_out, int out_size, void* d_ws, size_t ws_size,
                              hipStream_t stream) {
    const float* x   = (const float*)d_in[0];
    const float* u   = (const float*)d_in[1];
    const float* A   = (const float*)d_in[2];
    const float* B1  = (const float*)d_in[3];
    const float* B2  = (const float*)d_in[4];
    const float* C1  = (const float*)d_in[5];
    const float* D11 = (const float*)d_in[6];
    const float* D12 = (const float*)d_in[7];
    const float* bv  = (const float*)d_in[8];
    const float* bx  = (const float*)d_in[9];
    float* out = (float*)d_out;
    float* ws  = (float*)d_ws;

    prep_kernel<<<1, 256, 0, stream>>>(A, B1, B2, C1, D11, D12, bv, bx, ws);
    renl2_kernel<<<NROWS / 64, 64, 0, stream>>>(x, u, ws, out);
}